// Round 8
// baseline (168.817 us; speedup 1.0000x reference)
//
#include <hip/hip_runtime.h>
#include <stdint.h>

#define HID 2560
#define NH 80
#define PDIM 64
#define NDIM 128
#define INTER 5120
#define CONV_DIM 5376
#define PROJ_DIM 10576
#define NBATCH 64
#define EPS_ 1e-5f
#define NF4_IN  6768640LL   // 10576*2560/4
#define NF4_OUT 3276800LL   // 2560*5120/4

typedef short short8 __attribute__((ext_vector_type(8)));
typedef float f32x4 __attribute__((ext_vector_type(4)));

__device__ __forceinline__ unsigned short f2bf(float f){
  unsigned u = __builtin_bit_cast(unsigned, f);
  u += 0x7FFFu + ((u >> 16) & 1u);
  return (unsigned short)(u >> 16);
}
__device__ __forceinline__ float silu_(float x){ return x / (1.f + __expf(-x)); }

// ---------------- K_cvt_in: W_in f32 -> bf16, fragment-tile layout ----------------
// Wb[(n>>4)*40960 + (k>>5)*512 + (n&15)*32 + (k&31)]
__global__ __launch_bounds__(256) void k_cvt_in(const float* __restrict__ w,
                                                unsigned short* __restrict__ wb){
  for (long long i = (long long)blockIdx.x * 256 + threadIdx.x; i < NF4_IN;
       i += (long long)gridDim.x * 256){
    int n = (int)(i / 640);
    int k = (int)(i - (long long)n * 640) * 4;
    float4 v = ((const float4*)w)[i];
    ushort4 o; o.x=f2bf(v.x); o.y=f2bf(v.y); o.z=f2bf(v.z); o.w=f2bf(v.w);
    *(ushort4*)(wb + (size_t)(n >> 4) * 40960 + (k >> 5) * 512 + (n & 15) * 32 + (k & 31)) = o;
  }
}
// ---------------- K_cvt_out: W_out f32 -> bf16, fragment-tile layout ----------------
// Wb[(n>>4)*81920 + (k>>5)*512 + (n&15)*32 + (k&31)]
__global__ __launch_bounds__(256) void k_cvt_out(const float* __restrict__ w,
                                                 unsigned short* __restrict__ wb){
  for (long long i = (long long)blockIdx.x * 256 + threadIdx.x; i < NF4_OUT;
       i += (long long)gridDim.x * 256){
    int n = (int)(i / 1280);
    int k = (int)(i - (long long)n * 1280) * 4;
    float4 v = ((const float4*)w)[i];
    ushort4 o; o.x=f2bf(v.x); o.y=f2bf(v.y); o.z=f2bf(v.z); o.w=f2bf(v.w);
    *(ushort4*)(wb + (size_t)(n >> 4) * 81920 + (k >> 5) * 512 + (n & 15) * 32 + (k & 31)) = o;
  }
}

// ---------------- K_dt: exact f32 dt partials + X->bf16 (k-major [s][b][32]) ----------------
__global__ __launch_bounds__(256) void k_dt(const float* __restrict__ X,
                                            const float* __restrict__ W,
                                            float* __restrict__ dt_part,
                                            unsigned short* __restrict__ Xb){
  const int h = blockIdx.x, ks = blockIdx.y;
  const int tid = threadIdx.x, wid = tid >> 6, lane = tid & 63;
  const float* wr = W + (size_t)(INTER + CONV_DIM + h) * HID + ks * 320;
  float w[5];
  #pragma unroll
  for (int i = 0; i < 5; ++i) w[i] = wr[lane + i * 64];
  #pragma unroll
  for (int bi = 0; bi < 16; ++bi){
    const int b = wid * 16 + bi;
    const float* xr = X + (size_t)b * HID + ks * 320;
    float x[5];
    float acc = 0.f;
    #pragma unroll
    for (int i = 0; i < 5; ++i){ x[i] = xr[lane + i * 64]; acc += x[i] * w[i]; }
    if (h == 0){
      #pragma unroll
      for (int i = 0; i < 5; ++i){
        const int k = ks * 320 + lane + i * 64;
        Xb[(k >> 5) * 2048 + b * 32 + (k & 31)] = f2bf(x[i]);
      }
    }
    #pragma unroll
    for (int m = 32; m; m >>= 1) acc += __shfl_xor(acc, m);
    if (lane == 0) dt_part[(ks * NBATCH + b) * NH + h] = acc;
  }
}

// ---------------- K1: proj = X @ W_in^T — contiguous fragment-tile streams ----------------
__global__ __launch_bounds__(64) void k1_proj(const unsigned short* __restrict__ Xb,
                                              const unsigned short* __restrict__ Wb,
                                              float* __restrict__ proj){
  const int lane = threadIdx.x;
  const int lr = lane & 15, lg = lane >> 4;
  const int bx = blockIdx.x;
  const int n0 = bx * 16;
  const short* ap = (const short*)Xb + lr * 32 + lg * 8;
  const short* bp = (const short*)Wb + (size_t)bx * 40960 + lr * 32 + lg * 8;
  f32x4 acc0 = {0,0,0,0}, acc1 = {0,0,0,0}, acc2 = {0,0,0,0}, acc3 = {0,0,0,0};
  #pragma unroll 8
  for (int s = 0; s < 80; ++s){
    short8 a0 = *(const short8*)(ap + s * 2048);
    short8 a1 = *(const short8*)(ap + s * 2048 + 512);
    short8 a2 = *(const short8*)(ap + s * 2048 + 1024);
    short8 a3 = *(const short8*)(ap + s * 2048 + 1536);
    short8 bb = *(const short8*)(bp + s * 512);
    acc0 = __builtin_amdgcn_mfma_f32_16x16x32_bf16(a0, bb, acc0, 0, 0, 0);
    acc1 = __builtin_amdgcn_mfma_f32_16x16x32_bf16(a1, bb, acc1, 0, 0, 0);
    acc2 = __builtin_amdgcn_mfma_f32_16x16x32_bf16(a2, bb, acc2, 0, 0, 0);
    acc3 = __builtin_amdgcn_mfma_f32_16x16x32_bf16(a3, bb, acc3, 0, 0, 0);
  }
  #pragma unroll
  for (int r = 0; r < 4; ++r){
    const int m = lg * 4 + r;
    proj[(size_t)(m     ) * PROJ_DIM + n0 + lr] = acc0[r];
    proj[(size_t)(m + 16) * PROJ_DIM + n0 + lr] = acc1[r];
    proj[(size_t)(m + 32) * PROJ_DIM + n0 + lr] = acc2[r];
    proj[(size_t)(m + 48) * PROJ_DIM + n0 + lr] = acc3[r];
  }
}

// ---------------- K2a: conv+silu; dt finalize; B·C ----------------
__global__ __launch_bounds__(256) void k2a(const float* __restrict__ cs,
                                           const float* __restrict__ cw,
                                           const float* __restrict__ cb,
                                           const float* __restrict__ proj,
                                           const float* __restrict__ dt_part,
                                           const float* __restrict__ dt_bias,
                                           const float* __restrict__ A_log,
                                           float* __restrict__ hs_bc,
                                           float* __restrict__ dt_sp,
                                           float* __restrict__ dAv,
                                           float* __restrict__ s_bc){
  const int b = blockIdx.y;
  const int c0 = blockIdx.x * 384;
  const int tid = threadIdx.x;
  __shared__ float bc[384];
  for (int i = tid; i < 384; i += 256){
    const int c = c0 + i;
    float4 s4 = *(const float4*)(cs + ((size_t)b * CONV_DIM + c) * 4);
    float4 w4 = *(const float4*)(cw + (size_t)c * 4);
    float hbc = proj[(size_t)b * PROJ_DIM + INTER + c];
    float x = s4.y * w4.x + s4.z * w4.y + s4.w * w4.z + hbc * w4.w + cb[c];
    float v = silu_(x);
    hs_bc[(size_t)b * CONV_DIM + c] = v;
    if (blockIdx.x == 13) bc[i] = v;
  }
  if (blockIdx.x == 0 && tid < NH){
    float acc = dt_bias[tid];
    #pragma unroll
    for (int ks = 0; ks < 8; ++ks) acc += dt_part[(ks * NBATCH + b) * NH + tid];
    float sp = acc > 15.f ? acc : log1pf(__expf(acc));
    sp = fminf(fmaxf(sp, 0.f), 100.f);
    dt_sp[b * NH + tid] = sp;
    dAv[b * NH + tid] = __expf(-sp * __expf(A_log[tid]));
  }
  if (blockIdx.x == 13){
    __syncthreads();
    if (tid < 64){
      float p = bc[128 + tid] * bc[256 + tid] + bc[192 + tid] * bc[320 + tid];
      #pragma unroll
      for (int m = 32; m; m >>= 1) p += __shfl_xor(p, m);
      if (tid == 0) s_bc[b] = p;
    }
  }
}

// ---------------- K2b: SSM step, gate, yf (k-major Yb) + sumsq partials ----------------
__global__ __launch_bounds__(256) void k2b(const float* __restrict__ ssm,
                                           const float* __restrict__ hs_bc,
                                           const float* __restrict__ proj,
                                           const float* __restrict__ dt_sp,
                                           const float* __restrict__ dAv,
                                           const float* __restrict__ s_bc,
                                           const float* __restrict__ Dp,
                                           const float* __restrict__ norm_w,
                                           unsigned short* __restrict__ yfb,
                                           float* __restrict__ ssq_part){
  const int h = blockIdx.x, b = blockIdx.y;
  const int tid = threadIdx.x;
  const int wid = tid >> 6, lane = tid & 63;
  const int lr = lane & 15, lg = lane >> 4;
  const float dA_s = dAv[b * NH + h];
  const float coef = dt_sp[b * NH + h] * s_bc[b] + Dp[h];
  const float* Cb = hs_bc + (size_t)b * CONV_DIM + INTER + NDIM;
  float4 c0 = *(const float4*)(Cb + lr * 8);
  float4 c1 = *(const float4*)(Cb + lr * 8 + 4);
  const float* srow = ssm + ((size_t)b * NH + h) * PDIM * NDIM;
  float ssq = 0.f;
  __shared__ float ssql[4];
  #pragma unroll
  for (int r = 0; r < 4; ++r){
    const int p = wid * 16 + r * 4 + lg;
    const float* sp_ = srow + (size_t)p * NDIM + lr * 8;
    float4 v0 = *(const float4*)(sp_);
    float4 v1 = *(const float4*)(sp_ + 4);
    float dot = v0.x*c0.x + v0.y*c0.y + v0.z*c0.z + v0.w*c0.w
              + v1.x*c1.x + v1.y*c1.y + v1.z*c1.z + v1.w*c1.w;
    dot += __shfl_xor(dot, 1); dot += __shfl_xor(dot, 2);
    dot += __shfl_xor(dot, 4); dot += __shfl_xor(dot, 8);
    if (lr == 0){
      const int hp = h * PDIM + p;
      float hs = hs_bc[(size_t)b * CONV_DIM + hp];
      float y = dA_s * dot + hs * coef;
      float g = proj[(size_t)b * PROJ_DIM + hp];
      float yf = y * silu_(g) * norm_w[hp];
      yfb[(hp >> 5) * 2048 + b * 32 + (hp & 31)] = f2bf(yf);
      ssq += yf * yf;
    }
  }
  #pragma unroll
  for (int m = 32; m; m >>= 1) ssq += __shfl_xor(ssq, m);
  if (lane == 0) ssql[wid] = ssq;
  __syncthreads();
  if (tid == 0) ssq_part[b * NH + h] = ssql[0] + ssql[1] + ssql[2] + ssql[3];
}

// ---------------- K3: out partials = Yb @ Wb_out^T — contiguous streams ----------------
__global__ __launch_bounds__(64) void k3_out(const unsigned short* __restrict__ Yb,
                                             const unsigned short* __restrict__ Wb,
                                             float* __restrict__ part){
  const int lane = threadIdx.x;
  const int lr = lane & 15, lg = lane >> 4;
  const int bx = blockIdx.x;
  const int n0 = bx * 16;
  const int ks = blockIdx.y;
  const short* ap = (const short*)Yb + lr * 32 + lg * 8;
  const short* bp = (const short*)Wb + (size_t)bx * 81920 + lr * 32 + lg * 8;
  f32x4 acc0 = {0,0,0,0}, acc1 = {0,0,0,0}, acc2 = {0,0,0,0}, acc3 = {0,0,0,0};
  #pragma unroll 8
  for (int t = 0; t < 40; ++t){
    const int s = ks * 40 + t;
    short8 a0 = *(const short8*)(ap + s * 2048);
    short8 a1 = *(const short8*)(ap + s * 2048 + 512);
    short8 a2 = *(const short8*)(ap + s * 2048 + 1024);
    short8 a3 = *(const short8*)(ap + s * 2048 + 1536);
    short8 bb = *(const short8*)(bp + s * 512);
    acc0 = __builtin_amdgcn_mfma_f32_16x16x32_bf16(a0, bb, acc0, 0, 0, 0);
    acc1 = __builtin_amdgcn_mfma_f32_16x16x32_bf16(a1, bb, acc1, 0, 0, 0);
    acc2 = __builtin_amdgcn_mfma_f32_16x16x32_bf16(a2, bb, acc2, 0, 0, 0);
    acc3 = __builtin_amdgcn_mfma_f32_16x16x32_bf16(a3, bb, acc3, 0, 0, 0);
  }
  float* pt = part + (size_t)ks * NBATCH * 2560;
  #pragma unroll
  for (int r = 0; r < 4; ++r){
    const int m = lg * 4 + r;
    pt[(size_t)(m     ) * 2560 + n0 + lr] = acc0[r];
    pt[(size_t)(m + 16) * 2560 + n0 + lr] = acc1[r];
    pt[(size_t)(m + 32) * 2560 + n0 + lr] = acc2[r];
    pt[(size_t)(m + 48) * 2560 + n0 + lr] = acc3[r];
  }
}

// ---------------- K4: reduce K-partials, apply rsqrt(mean(yf^2)+eps) ----------------
__global__ __launch_bounds__(256) void k4_norm(const float* __restrict__ part,
                                               const float* __restrict__ ssq_part,
                                               float* __restrict__ out){
  const int b = blockIdx.y;
  const int tid = threadIdx.x;
  __shared__ float w4[4];
  __shared__ float sc;
  float v = (tid < NH) ? ssq_part[b * NH + tid] : 0.f;
  #pragma unroll
  for (int m = 32; m; m >>= 1) v += __shfl_xor(v, m);
  const int wid = tid >> 6, lane = tid & 63;
  if (lane == 0) w4[wid] = v;
  __syncthreads();
  if (tid == 0){
    float total = w4[0] + w4[1] + w4[2] + w4[3];
    sc = rsqrtf(total / (float)INTER + EPS_);
  }
  __syncthreads();
  const int j = blockIdx.x * 256 + tid;
  const size_t idx = (size_t)b * 2560 + j;
  const size_t plane = (size_t)NBATCH * 2560;
  float s = part[idx] + part[plane + idx] + part[2*plane + idx] + part[3*plane + idx];
  out[idx] = sc * s;
}

extern "C" void kernel_launch(void* const* d_in, const int* in_sizes, int n_in,
                              void* d_out, int out_size, void* d_ws, size_t ws_size,
                              hipStream_t stream){
  const float* x_in       = (const float*)d_in[0];
  const float* conv_state = (const float*)d_in[1];
  const float* ssm_state  = (const float*)d_in[2];
  const float* in_proj_w  = (const float*)d_in[3];
  const float* conv_w     = (const float*)d_in[4];
  const float* conv_b     = (const float*)d_in[5];
  const float* dt_bias    = (const float*)d_in[6];
  const float* A_log      = (const float*)d_in[7];
  const float* Dp         = (const float*)d_in[8];
  const float* norm_w     = (const float*)d_in[9];
  const float* out_proj_w = (const float*)d_in[10];
  float* out = (float*)d_out;

  char* ws = (char*)d_ws;
  unsigned short* Xb    = (unsigned short*)(ws);            // 327,680 B  (k-major)
  float* dt_part        = (float*)(ws + 327680);            // 163,840 B
  float* proj           = (float*)(ws + 491520);            // 2,707,456 B
  float* hs_bc          = (float*)(ws + 3198976);           // 1,376,256 B
  float* dt_sp          = (float*)(ws + 4575232);           // 20,480 B
  float* dAv            = (float*)(ws + 4595712);           // 20,480 B
  float* s_bc           = (float*)(ws + 4616192);           // 256 B
  float* ssq            = (float*)(ws + 4616448);           // 20,480 B
  unsigned short* Yb    = (unsigned short*)(ws + 4636928);  // 655,360 B  (k-major)
  float* part           = (float*)(ws + 5292288);           // 2,621,440 B
  unsigned short* Wb_in = (unsigned short*)(ws + 8000000);  // 54,149,120 B (tile-major)
  unsigned short* Wb_out= (unsigned short*)(ws + 62149120); // 26,214,400 B (tile-major)

  k_cvt_in<<<dim3(2048), dim3(256), 0, stream>>>(in_proj_w, Wb_in);
  k_dt<<<dim3(NH, 8), dim3(256), 0, stream>>>(x_in, in_proj_w, dt_part, Xb);
  k1_proj<<<dim3(PROJ_DIM / 16), dim3(64), 0, stream>>>(Xb, Wb_in, proj);
  k2a<<<dim3(14, NBATCH), dim3(256), 0, stream>>>(conv_state, conv_w, conv_b, proj,
                                                  dt_part, dt_bias, A_log,
                                                  hs_bc, dt_sp, dAv, s_bc);
  k2b<<<dim3(NH, NBATCH), dim3(256), 0, stream>>>(ssm_state, hs_bc, proj, dt_sp, dAv,
                                                  s_bc, Dp, norm_w, Yb, ssq);
  k_cvt_out<<<dim3(1024), dim3(256), 0, stream>>>(out_proj_w, Wb_out);
  k3_out<<<dim3(160, 4), dim3(64), 0, stream>>>(Yb, Wb_out, part);
  k4_norm<<<dim3(10, NBATCH), dim3(256), 0, stream>>>(part, ssq, out);
}

// Round 9
// 134.878 us; speedup vs baseline: 1.2516x; 1.2516x over previous
//
#include <hip/hip_runtime.h>
#include <stdint.h>

#define HID 2560
#define NH 80
#define PDIM 64
#define NDIM 128
#define INTER 5120
#define CONV_DIM 5376
#define PROJ_DIM 10576
#define NBATCH 64
#define EPS_ 1e-5f

typedef short short8 __attribute__((ext_vector_type(8)));
typedef float f32x4 __attribute__((ext_vector_type(4)));

__device__ __forceinline__ unsigned short f2bf(float f){
  unsigned u = __builtin_bit_cast(unsigned, f);
  u += 0x7FFFu + ((u >> 16) & 1u);
  return (unsigned short)(u >> 16);
}
__device__ __forceinline__ float silu_(float x){ return x / (1.f + __expf(-x)); }

// ---------------- K_dt: exact f32 dt partials + X->bf16 conversion ----------------
__global__ __launch_bounds__(256) void k_dt(const float* __restrict__ X,
                                            const float* __restrict__ W,
                                            float* __restrict__ dt_part,
                                            unsigned short* __restrict__ Xb){
  const int h = blockIdx.x, ks = blockIdx.y;
  const int tid = threadIdx.x, wid = tid >> 6, lane = tid & 63;
  const float* wr = W + (size_t)(INTER + CONV_DIM + h) * HID + ks * 320;
  float w[5];
  #pragma unroll
  for (int i = 0; i < 5; ++i) w[i] = wr[lane + i * 64];
  #pragma unroll
  for (int bi = 0; bi < 16; ++bi){
    const int b = wid * 16 + bi;
    const float* xr = X + (size_t)b * HID + ks * 320;
    float x[5];
    float acc = 0.f;
    #pragma unroll
    for (int i = 0; i < 5; ++i){ x[i] = xr[lane + i * 64]; acc += x[i] * w[i]; }
    if (h == 0){
      #pragma unroll
      for (int i = 0; i < 5; ++i)
        Xb[(size_t)b * HID + ks * 320 + lane + i * 64] = f2bf(x[i]);
    }
    #pragma unroll
    for (int m = 32; m; m >>= 1) acc += __shfl_xor(acc, m);
    if (lane == 0) dt_part[(ks * NBATCH + b) * NH + h] = acc;
  }
}

// ---------------- K1: proj = X @ W_in^T — 4-stage register-prefetch pipeline ----------------
__global__ __launch_bounds__(64, 1) void k1_proj(const unsigned short* __restrict__ Xb,
                                                 const float* __restrict__ W,
                                                 float* __restrict__ proj){
  const int lane = threadIdx.x;
  const int lr = lane & 15, lg = lane >> 4;
  const int n0 = blockIdx.x * 16;
  const short* ap = (const short*)Xb + (size_t)lr * HID + lg * 8;
  const float* bp = W + (size_t)(n0 + lr) * HID + lg * 8;
  f32x4 acc0 = {0,0,0,0}, acc1 = {0,0,0,0}, acc2 = {0,0,0,0}, acc3 = {0,0,0,0};
  short8 A0[4], A1[4], A2[4], A3[4];
  float4 B0[4], B1[4];
  #pragma unroll
  for (int p = 0; p < 4; ++p){
    const int k = p * 32;
    A0[p] = *(const short8*)(ap + k);
    A1[p] = *(const short8*)(ap + 16 * HID + k);
    A2[p] = *(const short8*)(ap + 32 * HID + k);
    A3[p] = *(const short8*)(ap + 48 * HID + k);
    B0[p] = *(const float4*)(bp + k);
    B1[p] = *(const float4*)(bp + k + 4);
  }
  #pragma unroll 4
  for (int s = 0; s < 76; ++s){
    const int p = s & 3;           // compile-time constant in each unrolled copy
    short8 bb;
    bb[0]=(short)f2bf(B0[p].x); bb[1]=(short)f2bf(B0[p].y);
    bb[2]=(short)f2bf(B0[p].z); bb[3]=(short)f2bf(B0[p].w);
    bb[4]=(short)f2bf(B1[p].x); bb[5]=(short)f2bf(B1[p].y);
    bb[6]=(short)f2bf(B1[p].z); bb[7]=(short)f2bf(B1[p].w);
    acc0 = __builtin_amdgcn_mfma_f32_16x16x32_bf16(A0[p], bb, acc0, 0, 0, 0);
    acc1 = __builtin_amdgcn_mfma_f32_16x16x32_bf16(A1[p], bb, acc1, 0, 0, 0);
    acc2 = __builtin_amdgcn_mfma_f32_16x16x32_bf16(A2[p], bb, acc2, 0, 0, 0);
    acc3 = __builtin_amdgcn_mfma_f32_16x16x32_bf16(A3[p], bb, acc3, 0, 0, 0);
    const int k = (s + 4) * 32;    // refill the slot just consumed
    A0[p] = *(const short8*)(ap + k);
    A1[p] = *(const short8*)(ap + 16 * HID + k);
    A2[p] = *(const short8*)(ap + 32 * HID + k);
    A3[p] = *(const short8*)(ap + 48 * HID + k);
    B0[p] = *(const float4*)(bp + k);
    B1[p] = *(const float4*)(bp + k + 4);
  }
  #pragma unroll
  for (int s = 76; s < 80; ++s){
    const int p = s & 3;
    short8 bb;
    bb[0]=(short)f2bf(B0[p].x); bb[1]=(short)f2bf(B0[p].y);
    bb[2]=(short)f2bf(B0[p].z); bb[3]=(short)f2bf(B0[p].w);
    bb[4]=(short)f2bf(B1[p].x); bb[5]=(short)f2bf(B1[p].y);
    bb[6]=(short)f2bf(B1[p].z); bb[7]=(short)f2bf(B1[p].w);
    acc0 = __builtin_amdgcn_mfma_f32_16x16x32_bf16(A0[p], bb, acc0, 0, 0, 0);
    acc1 = __builtin_amdgcn_mfma_f32_16x16x32_bf16(A1[p], bb, acc1, 0, 0, 0);
    acc2 = __builtin_amdgcn_mfma_f32_16x16x32_bf16(A2[p], bb, acc2, 0, 0, 0);
    acc3 = __builtin_amdgcn_mfma_f32_16x16x32_bf16(A3[p], bb, acc3, 0, 0, 0);
  }
  #pragma unroll
  for (int r = 0; r < 4; ++r){
    const int m = lg * 4 + r;
    proj[(size_t)(m     ) * PROJ_DIM + n0 + lr] = acc0[r];
    proj[(size_t)(m + 16) * PROJ_DIM + n0 + lr] = acc1[r];
    proj[(size_t)(m + 32) * PROJ_DIM + n0 + lr] = acc2[r];
    proj[(size_t)(m + 48) * PROJ_DIM + n0 + lr] = acc3[r];
  }
}

// ---------------- K2a: conv+silu; dt finalize; B·C ----------------
__global__ __launch_bounds__(256) void k2a(const float* __restrict__ cs,
                                           const float* __restrict__ cw,
                                           const float* __restrict__ cb,
                                           const float* __restrict__ proj,
                                           const float* __restrict__ dt_part,
                                           const float* __restrict__ dt_bias,
                                           const float* __restrict__ A_log,
                                           float* __restrict__ hs_bc,
                                           float* __restrict__ dt_sp,
                                           float* __restrict__ dAv,
                                           float* __restrict__ s_bc){
  const int b = blockIdx.y;
  const int c0 = blockIdx.x * 384;
  const int tid = threadIdx.x;
  __shared__ float bc[384];
  for (int i = tid; i < 384; i += 256){
    const int c = c0 + i;
    float4 s4 = *(const float4*)(cs + ((size_t)b * CONV_DIM + c) * 4);
    float4 w4 = *(const float4*)(cw + (size_t)c * 4);
    float hbc = proj[(size_t)b * PROJ_DIM + INTER + c];
    float x = s4.y * w4.x + s4.z * w4.y + s4.w * w4.z + hbc * w4.w + cb[c];
    float v = silu_(x);
    hs_bc[(size_t)b * CONV_DIM + c] = v;
    if (blockIdx.x == 13) bc[i] = v;
  }
  if (blockIdx.x == 0 && tid < NH){
    float acc = dt_bias[tid];
    #pragma unroll
    for (int ks = 0; ks < 8; ++ks) acc += dt_part[(ks * NBATCH + b) * NH + tid];
    float sp = acc > 15.f ? acc : log1pf(__expf(acc));
    sp = fminf(fmaxf(sp, 0.f), 100.f);
    dt_sp[b * NH + tid] = sp;
    dAv[b * NH + tid] = __expf(-sp * __expf(A_log[tid]));
  }
  if (blockIdx.x == 13){
    __syncthreads();
    if (tid < 64){
      float p = bc[128 + tid] * bc[256 + tid] + bc[192 + tid] * bc[320 + tid];
      #pragma unroll
      for (int m = 32; m; m >>= 1) p += __shfl_xor(p, m);
      if (tid == 0) s_bc[b] = p;
    }
  }
}

// ---------------- K2b: SSM step, gate, yf + sumsq partials (block = (h,b)) ----------------
__global__ __launch_bounds__(256) void k2b(const float* __restrict__ ssm,
                                           const float* __restrict__ hs_bc,
                                           const float* __restrict__ proj,
                                           const float* __restrict__ dt_sp,
                                           const float* __restrict__ dAv,
                                           const float* __restrict__ s_bc,
                                           const float* __restrict__ Dp,
                                           const float* __restrict__ norm_w,
                                           unsigned short* __restrict__ yfb,
                                           float* __restrict__ ssq_part){
  const int h = blockIdx.x, b = blockIdx.y;
  const int tid = threadIdx.x;
  const int wid = tid >> 6, lane = tid & 63;
  const int lr = lane & 15, lg = lane >> 4;
  const float dA_s = dAv[b * NH + h];
  const float coef = dt_sp[b * NH + h] * s_bc[b] + Dp[h];
  const float* Cb = hs_bc + (size_t)b * CONV_DIM + INTER + NDIM;
  float4 c0 = *(const float4*)(Cb + lr * 8);
  float4 c1 = *(const float4*)(Cb + lr * 8 + 4);
  const float* srow = ssm + ((size_t)b * NH + h) * PDIM * NDIM;
  float ssq = 0.f;
  __shared__ float ssql[4];
  #pragma unroll
  for (int r = 0; r < 4; ++r){
    const int p = wid * 16 + r * 4 + lg;
    const float* sp_ = srow + (size_t)p * NDIM + lr * 8;
    float4 v0 = *(const float4*)(sp_);
    float4 v1 = *(const float4*)(sp_ + 4);
    float dot = v0.x*c0.x + v0.y*c0.y + v0.z*c0.z + v0.w*c0.w
              + v1.x*c1.x + v1.y*c1.y + v1.z*c1.z + v1.w*c1.w;
    dot += __shfl_xor(dot, 1); dot += __shfl_xor(dot, 2);
    dot += __shfl_xor(dot, 4); dot += __shfl_xor(dot, 8);
    if (lr == 0){
      const int hp = h * PDIM + p;
      float hs = hs_bc[(size_t)b * CONV_DIM + hp];
      float y = dA_s * dot + hs * coef;
      float g = proj[(size_t)b * PROJ_DIM + hp];
      float yf = y * silu_(g) * norm_w[hp];
      yfb[(size_t)b * INTER + hp] = f2bf(yf);
      ssq += yf * yf;
    }
  }
  #pragma unroll
  for (int m = 32; m; m >>= 1) ssq += __shfl_xor(ssq, m);
  if (lane == 0) ssql[wid] = ssq;
  __syncthreads();
  if (tid == 0) ssq_part[b * NH + h] = ssql[0] + ssql[1] + ssql[2] + ssql[3];
}

// ---------------- K3: out partials = yf_bf16 @ W_out^T — 4-stage pipeline ----------------
__global__ __launch_bounds__(64, 1) void k3_out(const unsigned short* __restrict__ Yb,
                                                const float* __restrict__ W,
                                                float* __restrict__ part){
  const int lane = threadIdx.x;
  const int lr = lane & 15, lg = lane >> 4;
  const int n0 = blockIdx.x * 16;
  const int ks = blockIdx.y;
  const int kb = ks * 1280;
  const short* ap = (const short*)Yb + (size_t)lr * INTER + kb + lg * 8;
  const float* bp = W + (size_t)(n0 + lr) * INTER + kb + lg * 8;
  f32x4 acc0 = {0,0,0,0}, acc1 = {0,0,0,0}, acc2 = {0,0,0,0}, acc3 = {0,0,0,0};
  short8 A0[4], A1[4], A2[4], A3[4];
  float4 B0[4], B1[4];
  #pragma unroll
  for (int p = 0; p < 4; ++p){
    const int k = p * 32;
    A0[p] = *(const short8*)(ap + k);
    A1[p] = *(const short8*)(ap + 16 * INTER + k);
    A2[p] = *(const short8*)(ap + 32 * INTER + k);
    A3[p] = *(const short8*)(ap + 48 * INTER + k);
    B0[p] = *(const float4*)(bp + k);
    B1[p] = *(const float4*)(bp + k + 4);
  }
  #pragma unroll 4
  for (int s = 0; s < 36; ++s){
    const int p = s & 3;
    short8 bb;
    bb[0]=(short)f2bf(B0[p].x); bb[1]=(short)f2bf(B0[p].y);
    bb[2]=(short)f2bf(B0[p].z); bb[3]=(short)f2bf(B0[p].w);
    bb[4]=(short)f2bf(B1[p].x); bb[5]=(short)f2bf(B1[p].y);
    bb[6]=(short)f2bf(B1[p].z); bb[7]=(short)f2bf(B1[p].w);
    acc0 = __builtin_amdgcn_mfma_f32_16x16x32_bf16(A0[p], bb, acc0, 0, 0, 0);
    acc1 = __builtin_amdgcn_mfma_f32_16x16x32_bf16(A1[p], bb, acc1, 0, 0, 0);
    acc2 = __builtin_amdgcn_mfma_f32_16x16x32_bf16(A2[p], bb, acc2, 0, 0, 0);
    acc3 = __builtin_amdgcn_mfma_f32_16x16x32_bf16(A3[p], bb, acc3, 0, 0, 0);
    const int k = (s + 4) * 32;
    A0[p] = *(const short8*)(ap + k);
    A1[p] = *(const short8*)(ap + 16 * INTER + k);
    A2[p] = *(const short8*)(ap + 32 * INTER + k);
    A3[p] = *(const short8*)(ap + 48 * INTER + k);
    B0[p] = *(const float4*)(bp + k);
    B1[p] = *(const float4*)(bp + k + 4);
  }
  #pragma unroll
  for (int s = 36; s < 40; ++s){
    const int p = s & 3;
    short8 bb;
    bb[0]=(short)f2bf(B0[p].x); bb[1]=(short)f2bf(B0[p].y);
    bb[2]=(short)f2bf(B0[p].z); bb[3]=(short)f2bf(B0[p].w);
    bb[4]=(short)f2bf(B1[p].x); bb[5]=(short)f2bf(B1[p].y);
    bb[6]=(short)f2bf(B1[p].z); bb[7]=(short)f2bf(B1[p].w);
    acc0 = __builtin_amdgcn_mfma_f32_16x16x32_bf16(A0[p], bb, acc0, 0, 0, 0);
    acc1 = __builtin_amdgcn_mfma_f32_16x16x32_bf16(A1[p], bb, acc1, 0, 0, 0);
    acc2 = __builtin_amdgcn_mfma_f32_16x16x32_bf16(A2[p], bb, acc2, 0, 0, 0);
    acc3 = __builtin_amdgcn_mfma_f32_16x16x32_bf16(A3[p], bb, acc3, 0, 0, 0);
  }
  float* pt = part + (size_t)ks * NBATCH * 2560;
  #pragma unroll
  for (int r = 0; r < 4; ++r){
    const int m = lg * 4 + r;
    pt[(size_t)(m     ) * 2560 + n0 + lr] = acc0[r];
    pt[(size_t)(m + 16) * 2560 + n0 + lr] = acc1[r];
    pt[(size_t)(m + 32) * 2560 + n0 + lr] = acc2[r];
    pt[(size_t)(m + 48) * 2560 + n0 + lr] = acc3[r];
  }
}

// ---------------- K4: reduce K-partials, apply rsqrt(mean(yf^2)+eps) ----------------
__global__ __launch_bounds__(256) void k4_norm(const float* __restrict__ part,
                                               const float* __restrict__ ssq_part,
                                               float* __restrict__ out){
  const int b = blockIdx.y;
  const int tid = threadIdx.x;
  __shared__ float w4[4];
  __shared__ float sc;
  float v = (tid < NH) ? ssq_part[b * NH + tid] : 0.f;
  #pragma unroll
  for (int m = 32; m; m >>= 1) v += __shfl_xor(v, m);
  const int wid = tid >> 6, lane = tid & 63;
  if (lane == 0) w4[wid] = v;
  __syncthreads();
  if (tid == 0){
    float total = w4[0] + w4[1] + w4[2] + w4[3];
    sc = rsqrtf(total / (float)INTER + EPS_);
  }
  __syncthreads();
  const int j = blockIdx.x * 256 + tid;
  const size_t idx = (size_t)b * 2560 + j;
  const size_t plane = (size_t)NBATCH * 2560;
  float s = part[idx] + part[plane + idx] + part[2*plane + idx] + part[3*plane + idx];
  out[idx] = sc * s;
}

extern "C" void kernel_launch(void* const* d_in, const int* in_sizes, int n_in,
                              void* d_out, int out_size, void* d_ws, size_t ws_size,
                              hipStream_t stream){
  const float* x_in       = (const float*)d_in[0];
  const float* conv_state = (const float*)d_in[1];
  const float* ssm_state  = (const float*)d_in[2];
  const float* in_proj_w  = (const float*)d_in[3];
  const float* conv_w     = (const float*)d_in[4];
  const float* conv_b     = (const float*)d_in[5];
  const float* dt_bias    = (const float*)d_in[6];
  const float* A_log      = (const float*)d_in[7];
  const float* Dp         = (const float*)d_in[8];
  const float* norm_w     = (const float*)d_in[9];
  const float* out_proj_w = (const float*)d_in[10];
  float* out = (float*)d_out;

  char* ws = (char*)d_ws;
  unsigned short* Xb   = (unsigned short*)(ws);            // 327,680 B
  float* dt_part       = (float*)(ws + 327680);            // 163,840 B
  float* proj          = (float*)(ws + 491520);            // 2,707,456 B
  float* hs_bc         = (float*)(ws + 3198976);           // 1,376,256 B
  float* dt_sp         = (float*)(ws + 4575232);           // 20,480 B
  float* dAv           = (float*)(ws + 4595712);           // 20,480 B
  float* s_bc          = (float*)(ws + 4616192);           // 256 B
  float* ssq           = (float*)(ws + 4616448);           // 20,480 B
  unsigned short* Yb   = (unsigned short*)(ws + 4636928);  // 655,360 B
  float* part          = (float*)(ws + 5292288);           // 2,621,440 B

  k_dt<<<dim3(NH, 8), dim3(256), 0, stream>>>(x_in, in_proj_w, dt_part, Xb);
  k1_proj<<<dim3(PROJ_DIM / 16), dim3(64), 0, stream>>>(Xb, in_proj_w, proj);
  k2a<<<dim3(14, NBATCH), dim3(256), 0, stream>>>(conv_state, conv_w, conv_b, proj,
                                                  dt_part, dt_bias, A_log,
                                                  hs_bc, dt_sp, dAv, s_bc);
  k2b<<<dim3(NH, NBATCH), dim3(256), 0, stream>>>(ssm_state, hs_bc, proj, dt_sp, dAv,
                                                  s_bc, Dp, norm_w, Yb, ssq);
  k3_out<<<dim3(160, 4), dim3(64), 0, stream>>>(Yb, out_proj_w, part);
  k4_norm<<<dim3(10, NBATCH), dim3(256), 0, stream>>>(part, ssq, out);
}